// Round 12
// baseline (91.089 us; speedup 1.0000x reference)
//
#include <hip/hip_runtime.h>

using bf16x8 = __attribute__((ext_vector_type(8))) short;
using f32x4  = __attribute__((ext_vector_type(4))) float;

#define ND      2048
#define NOUT    192
#define TSEQ    4096
#define NCH     32            // 2048 / 64
#define ZP      196           // zbuf row stride (floats; 192 used, 16B-aligned)

#define OFF_PRE  4194304      // K*B*T*16
#define OFF_POST 5242880      // + K*B*T*4

__device__ __forceinline__ float sigmoidf_(float v) {
    return 1.0f / (1.0f + __expf(-v));
}
__device__ __forceinline__ unsigned f2bf(float f) {   // RNE float->bf16 bits
    unsigned u = __float_as_uint(f);
    u += 0x7fffu + ((u >> 16) & 1u);
    return u >> 16;
}
// robust to active_idx arriving as int32 or int64 (low-word read)
__device__ __forceinline__ int get_expert(const int* __restrict__ act, int k) {
    const bool odd_zero = (act[1] == 0) & (act[3] == 0) & (act[5] == 0) & (act[7] == 0);
    const bool even_any = (act[0] | act[2] | act[4] | act[6]) != 0;
    const bool is64 = odd_zero & even_any;
    return is64 ? act[2 * k] : act[k];
}

// -------- pass 1: Wb[o][d] = bf16( phi[e_k, j, d] * norm_w[e_k, d] ) --------
__global__ __launch_bounds__(256) void prep_w_kernel(
    const float* __restrict__ norm_w,
    const float* __restrict__ p_pre,
    const float* __restrict__ p_post,
    const float* __restrict__ p_res,
    const int* __restrict__ act,
    short* __restrict__ Wb)
{
    const int o = blockIdx.x;           // 0..191
    const int k = o / 24, j = o % 24;
    const int e = get_expert(act, k);
    const float* src;
    if (j < 4)      src = p_pre  + ((size_t)e * 4  + j)       * ND;
    else if (j < 8) src = p_post + ((size_t)e * 4  + (j - 4)) * ND;
    else            src = p_res  + ((size_t)e * 16 + (j - 8)) * ND;
    const float* nw = norm_w + (size_t)e * ND;
    short* dst = Wb + (size_t)o * ND;
    for (int d = threadIdx.x * 4; d < ND; d += 1024) {
        float4 a = *(const float4*)(src + d);
        float4 b = *(const float4*)(nw + d);
        uint2 w;
        w.x = f2bf(a.x * b.x) | (f2bf(a.y * b.y) << 16);
        w.y = f2bf(a.z * b.z) | (f2bf(a.w * b.w) << 16);
        *(uint2*)(dst + d) = w;
    }
}

// -------- pass 2: fused rms + MFMA GEMM + sigmoid/sinkhorn epilogue --------
// 512 blocks x 256 threads (4 waves) -- FROZEN R5/R9 geometry (every
// reparameterization failed: R2,R3,R7,R8,R10). New, value-preserving only:
//   * XCD-aware bijective block swizzle (512 = 8*64 exact): XCD x owns
//     contiguous tiles -> W (786 KB) becomes L2-resident per XCD, cutting
//     W-load latency in the stage-phase stall; X gets contiguous locality.
//   * non-temporal X loads + output stores (single-touch data; keep L2 for W)
//     via ext_vector f32x4 (HIP_vector_type float4 rejected by the builtin).
// ALL LDS staging accesses typed bf16x8 (uint4/bf16x8 mix broke R2/R3).
__global__ __launch_bounds__(256) void mhc_mfma_kernel(
    const float* __restrict__ xin,      // (B, 4, T, 512) fp32
    const short* __restrict__ Wb,       // (192, 2048) bf16 bits
    const int* __restrict__ act,
    const float* __restrict__ b_pre, const float* __restrict__ b_post,
    const float* __restrict__ b_res,
    const float* __restrict__ a_pre, const float* __restrict__ a_post,
    const float* __restrict__ a_res,
    float* __restrict__ out)
{
    __shared__ union SU {
        struct {
            alignas(16) short Xs[8 * 64 * 8];    // [g][m^g][8]  (8 KB)
            alignas(16) short Ws[8 * 192 * 8];   // [g][n^g][8]  (24 KB)
        } s;
        float zbuf[64][ZP];                      // 50.2 KB
    } u;
    __shared__ float inv_rms[64];

    const int tid  = threadIdx.x;
    const int lane = tid & 63;
    const int wid  = tid >> 6;
    const int wr = wid >> 1, wc = wid & 1;      // wave -> (rowgrp, colgrp)
    // XCD-aware bijective swizzle: dispatch round-robins XCDs; give XCD
    // (bid&7) the contiguous tile range (bid&7)*64 + (bid>>3).
    const int tile = ((blockIdx.x & 7) << 6) + (blockIdx.x >> 3);
    const int m0 = tile << 6;
    const int bb = m0 >> 12, t0 = m0 & (TSEQ - 1);
    const int gx  = tid & 7;                    // staging k-octet
    const int xmr = tid >> 3;                   // staging row (and +32)
    const int lrow = lane & 15, lhi = lane >> 4;

    f32x4 acc[2][6];
#pragma unroll
    for (int a_ = 0; a_ < 2; ++a_)
#pragma unroll
        for (int b_ = 0; b_ < 6; ++b_) {
            f32x4 z; z[0] = 0.f; z[1] = 0.f; z[2] = 0.f; z[3] = 0.f;
            acc[a_][b_] = z;
        }

    float ssq0 = 0.f, ssq1 = 0.f;
    f32x4 a0, a1, c0, c1;
    bf16x8 wv[6];

    auto issue_loads = [&](int ch) {
        const float* xb = xin
            + ((size_t)(bb * 4 + (ch >> 3)) * TSEQ + t0) * 512 + ((ch & 7) << 6);
        a0 = __builtin_nontemporal_load((const f32x4*)(xb + xmr * 512 + gx * 8));
        a1 = __builtin_nontemporal_load((const f32x4*)(xb + xmr * 512 + gx * 8 + 4));
        c0 = __builtin_nontemporal_load((const f32x4*)(xb + (xmr + 32) * 512 + gx * 8));
        c1 = __builtin_nontemporal_load((const f32x4*)(xb + (xmr + 32) * 512 + gx * 8 + 4));
        const short* wch = Wb + ch * 64;
#pragma unroll
        for (int j = 0; j < 6; ++j) {
            const int uidx = tid + 256 * j;     // 0..1535
            const int n = uidx >> 3, g = uidx & 7;
            wv[j] = *(const bf16x8*)(wch + n * 2048 + g * 8);   // cached: L2-resident
        }
    };

    issue_loads(0);                             // prologue

    for (int ch = 0; ch < NCH; ++ch) {
        __syncthreads();                        // (A) prev-chunk readers done

        // ---- convert + stage X (swizzled), accumulate ssq ----
        {
            ssq0 += a0[0]*a0[0] + a0[1]*a0[1] + a0[2]*a0[2] + a0[3]*a0[3]
                  + a1[0]*a1[0] + a1[1]*a1[1] + a1[2]*a1[2] + a1[3]*a1[3];
            bf16x8 pk;
            pk[0] = (short)f2bf(a0[0]); pk[1] = (short)f2bf(a0[1]);
            pk[2] = (short)f2bf(a0[2]); pk[3] = (short)f2bf(a0[3]);
            pk[4] = (short)f2bf(a1[0]); pk[5] = (short)f2bf(a1[1]);
            pk[6] = (short)f2bf(a1[2]); pk[7] = (short)f2bf(a1[3]);
            *(bf16x8*)&u.s.Xs[(gx * 64 + (xmr ^ gx)) * 8] = pk;
        }
        {
            ssq1 += c0[0]*c0[0] + c0[1]*c0[1] + c0[2]*c0[2] + c0[3]*c0[3]
                  + c1[0]*c1[0] + c1[1]*c1[1] + c1[2]*c1[2] + c1[3]*c1[3];
            bf16x8 pk;
            pk[0] = (short)f2bf(c0[0]); pk[1] = (short)f2bf(c0[1]);
            pk[2] = (short)f2bf(c0[2]); pk[3] = (short)f2bf(c0[3]);
            pk[4] = (short)f2bf(c1[0]); pk[5] = (short)f2bf(c1[1]);
            pk[6] = (short)f2bf(c1[2]); pk[7] = (short)f2bf(c1[3]);
            *(bf16x8*)&u.s.Xs[(gx * 64 + ((xmr + 32) ^ gx)) * 8] = pk;
        }
#pragma unroll
        for (int j = 0; j < 6; ++j) {
            const int uidx = tid + 256 * j;
            const int n = uidx >> 3, g = uidx & 7;
            *(bf16x8*)&u.s.Ws[(g * 192 + (n ^ g)) * 8] = wv[j];
        }
        __syncthreads();                        // (B) staged data visible

        // ---- prefetch next chunk: overlaps MFMA + next barrier wait ----
        if (ch + 1 < NCH) issue_loads(ch + 1);

        // ---- MFMA over chunk ----
#pragma unroll
        for (int ks = 0; ks < 2; ++ks) {
            const int g = ks * 4 + lhi;
            bf16x8 af[2], bfv[6];
#pragma unroll
            for (int mt = 0; mt < 2; ++mt)
                af[mt] = *(const bf16x8*)
                    &u.s.Xs[(g * 64 + ((wr * 32 + mt * 16 + lrow) ^ g)) * 8];
#pragma unroll
            for (int nt = 0; nt < 6; ++nt)
                bfv[nt] = *(const bf16x8*)
                    &u.s.Ws[(g * 192 + ((wc * 96 + nt * 16 + lrow) ^ g)) * 8];
#pragma unroll
            for (int mt = 0; mt < 2; ++mt)
#pragma unroll
                for (int nt = 0; nt < 6; ++nt)
                    acc[mt][nt] = __builtin_amdgcn_mfma_f32_16x16x32_bf16(
                        af[mt], bfv[nt], acc[mt][nt], 0, 0, 0);
        }
    }

    // ---- rms: 8-lane butterfly over gx (lanes xmr*8+gx are consecutive) ----
    ssq0 += __shfl_xor(ssq0, 1); ssq0 += __shfl_xor(ssq0, 2); ssq0 += __shfl_xor(ssq0, 4);
    ssq1 += __shfl_xor(ssq1, 1); ssq1 += __shfl_xor(ssq1, 2); ssq1 += __shfl_xor(ssq1, 4);
    if (gx == 0) {
        inv_rms[xmr]      = 1.0f / sqrtf(ssq0 * (1.0f / ND) + 1e-8f);
        inv_rms[xmr + 32] = 1.0f / sqrtf(ssq1 * (1.0f / ND) + 1e-8f);
    }
    __syncthreads();        // inv_rms visible; all MFMA LDS reads drained

    // ---- z scatter (C/D: col=lane&15, row=(lane>>4)*4+reg; R4 HW-probed) ----
#pragma unroll
    for (int mt = 0; mt < 2; ++mt) {
#pragma unroll
        for (int r = 0; r < 4; ++r) {
            const int row = wr * 32 + mt * 16 + lhi * 4 + r;
            const float ir = inv_rms[row];
#pragma unroll
            for (int nt = 0; nt < 6; ++nt) {
                const int n = wc * 96 + nt * 16 + lrow;
                u.zbuf[row][n] = acc[mt][nt][r] * ir;
            }
        }
    }
    __syncthreads();

    // ---- epilogue: 512 (row, k) problems, 2 per thread ----
#pragma unroll
    for (int pi = 0; pi < 2; ++pi) {
        const int p   = tid + pi * 256;
        const int row = p >> 3;
        const int k   = p & 7;
        const int e   = get_expert(act, k);

        float z[24];
#pragma unroll
        for (int j6 = 0; j6 < 6; ++j6) {
            float4 v = *(const float4*)&u.zbuf[row][k * 24 + j6 * 4];
            z[j6 * 4 + 0] = v.x; z[j6 * 4 + 1] = v.y;
            z[j6 * 4 + 2] = v.z; z[j6 * 4 + 3] = v.w;
        }

        const int m = m0 + row;
        const int b = m >> 12;
        const int t = m & (TSEQ - 1);
        const size_t kbt = (size_t)(k * 8 + b) * TSEQ + t;

        {   // H_pre
            const float al = a_pre[e];
            f32x4 o4;
            o4[0] = sigmoidf_(al * z[0] + b_pre[e * 4 + 0]);
            o4[1] = sigmoidf_(al * z[1] + b_pre[e * 4 + 1]);
            o4[2] = sigmoidf_(al * z[2] + b_pre[e * 4 + 2]);
            o4[3] = sigmoidf_(al * z[3] + b_pre[e * 4 + 3]);
            __builtin_nontemporal_store(o4, (f32x4*)(out + OFF_PRE + kbt * 4));
        }
        {   // H_post
            const float al = a_post[e];
            f32x4 o4;
            o4[0] = 2.f * sigmoidf_(al * z[4] + b_post[e * 4 + 0]);
            o4[1] = 2.f * sigmoidf_(al * z[5] + b_post[e * 4 + 1]);
            o4[2] = 2.f * sigmoidf_(al * z[6] + b_post[e * 4 + 2]);
            o4[3] = 2.f * sigmoidf_(al * z[7] + b_post[e * 4 + 3]);
            __builtin_nontemporal_store(o4, (f32x4*)(out + OFF_POST + kbt * 4));
        }
        {   // H_res: exp + 6x sinkhorn (row-normalize then col-normalize)
            const float al = a_res[e];
            float P[16];
#pragma unroll
            for (int mm = 0; mm < 16; ++mm)
                P[mm] = __expf(al * z[8 + mm] + b_res[e * 16 + mm]);
#pragma unroll
            for (int it = 0; it < 6; ++it) {
#pragma unroll
                for (int i = 0; i < 4; ++i) {
                    const float s = P[i*4] + P[i*4+1] + P[i*4+2] + P[i*4+3];
                    const float rs = 1.0f / s;
                    P[i*4] *= rs; P[i*4+1] *= rs; P[i*4+2] *= rs; P[i*4+3] *= rs;
                }
#pragma unroll
                for (int jj = 0; jj < 4; ++jj) {
                    const float s = P[jj] + P[4+jj] + P[8+jj] + P[12+jj];
                    const float rs = 1.0f / s;
                    P[jj] *= rs; P[4+jj] *= rs; P[8+jj] *= rs; P[12+jj] *= rs;
                }
            }
#pragma unroll
            for (int i = 0; i < 4; ++i) {
                f32x4 o4;
                o4[0] = P[i*4]; o4[1] = P[i*4+1]; o4[2] = P[i*4+2]; o4[3] = P[i*4+3];
                __builtin_nontemporal_store(o4, (f32x4*)(out + kbt * 16 + i * 4));
            }
        }
    }
}

extern "C" void kernel_launch(void* const* d_in, const int* in_sizes, int n_in,
                              void* d_out, int out_size, void* d_ws, size_t ws_size,
                              hipStream_t stream) {
    const float* x      = (const float*)d_in[0];
    const int*   act    = (const int*)d_in[1];
    const float* norm_w = (const float*)d_in[2];
    const float* p_pre  = (const float*)d_in[3];
    const float* p_post = (const float*)d_in[4];
    const float* p_res  = (const float*)d_in[5];
    const float* b_pre  = (const float*)d_in[6];
    const float* b_post = (const float*)d_in[7];
    const float* b_res  = (const float*)d_in[8];
    const float* a_pre  = (const float*)d_in[9];
    const float* a_post = (const float*)d_in[10];
    const float* a_res  = (const float*)d_in[11];
    short* Wb  = (short*)d_ws;              // 192*2048 bf16 = 786 KB
    float* out = (float*)d_out;

    prep_w_kernel<<<dim3(NOUT), dim3(256), 0, stream>>>(
        norm_w, p_pre, p_post, p_res, act, Wb);
    mhc_mfma_kernel<<<dim3(512), dim3(256), 0, stream>>>(
        x, Wb, act, b_pre, b_post, b_res, a_pre, a_post, a_res, out);
}